// Round 3
// baseline (205.539 us; speedup 1.0000x reference)
//
#include <hip/hip_runtime.h>
#include <stdint.h>

#define BATCH 16
#define CIN   64
#define COUT  64
#define NBR   8
#define HH    128
#define WW    128

#define RT 8
#define WT 32
#define SLABW 34                     // WT + 2 halo
#define SLABR 10                     // RT + 2 halo
#define SLABPIX (SLABR * SLABW)      // 340 pixels
#define SLABUS  (SLABPIX * 64)       // 21760 ushorts = 43520 B per tile slab
#define NTILES  (BATCH * (HH / RT) * (WW / WT))   // 1024

typedef __attribute__((ext_vector_type(8)))  short short8;
typedef __attribute__((ext_vector_type(16))) float f32x16;

// round-half-up f32->bf16 (inputs are tame normals; 3.4x error headroom measured)
__device__ __forceinline__ unsigned int f2bf_hi(float f) {
    union { float f; uint32_t u; } v; v.f = f;
    return (v.u + 0x8000u) >> 16;
}
// RNE version
__device__ __forceinline__ unsigned short f2bf(float f) {
    union { float f; uint32_t u; } v; v.f = f;
    uint32_t u = v.u;
    return (unsigned short)((u + 0x7FFFu + ((u >> 16) & 1u)) >> 16);
}
__device__ __forceinline__ short8 gld_frag(const unsigned short* p) {
    union { uint4 u; short8 s; } t;
    t.u = *(const uint4*)p;            // 16B aligned
    return t.s;
}
__device__ __forceinline__ short8 lds_frag128(const unsigned short* p) {
    union { uint4 u; short8 s; } t;
    t.u = *(const uint4*)p;            // 16B aligned b128 read
    return t.s;
}
// async global->LDS, 16B per lane; LDS dest must be wave-uniform base + lane*16
__device__ __forceinline__ void gload_lds16(const unsigned short* g, unsigned short* l) {
    __builtin_amdgcn_global_load_lds(
        (const __attribute__((address_space(1))) unsigned int*)g,
        (__attribute__((address_space(3))) unsigned int*)l, 16, 0, 0);
}

// ---------------- kernel 1: fused {softmax+filter combine} | {x -> swizzled tile slabs} ----
// blocks [0,1024): prep (b,o).  blocks [1024,2048): cast one conv tile's slab.
__global__ __launch_bounds__(256)
void k_pc(const float* __restrict__ cond,
          const float* __restrict__ sel_w,
          const float* __restrict__ sel_b,
          const float* __restrict__ filt_w,
          const float* __restrict__ filt_b,
          const float* __restrict__ x,
          unsigned short* __restrict__ wfilt,
          float* __restrict__ cbias,
          unsigned short* __restrict__ xt) {
    __shared__ float4 lw4[NBR * 144];          // 18432 B (prep branch only)
    __shared__ float lg[NBR];
    const int tid = threadIdx.x;

    if (blockIdx.x < NTILES) {
        // ---------------- prep branch ----------------
        float* lw = (float*)lw4;
        const int blk = blockIdx.x;
        const int b = blk >> 6, o = blk & 63;

        const float4* src4 = (const float4*)filt_w;
        #pragma unroll
        for (int i = tid; i < NBR * 144; i += 256)
            lw4[i] = src4[((i / 144) * COUT + o) * 144 + (i % 144)];

        {
            const int lane = tid & 63, w = tid >> 6;
            const float c0 = cond[b * CIN + lane];
            #pragma unroll
            for (int k = 0; k < 2; ++k) {
                const int n = w + k * 4;
                float p = c0 * sel_w[n * CIN + lane];
                #pragma unroll
                for (int off = 32; off > 0; off >>= 1)
                    p += __shfl_down(p, off, 64);
                if (lane == 0) lg[n] = p + sel_b[n];
            }
        }
        __syncthreads();

        float w8[NBR];
        {
            float m = -1e30f;
            #pragma unroll
            for (int n = 0; n < NBR; ++n) m = fmaxf(m, lg[n]);
            float s = 0.f;
            #pragma unroll
            for (int n = 0; n < NBR; ++n) { w8[n] = __expf(lg[n] - m); s += w8[n]; }
            const float inv = 1.f / s;
            #pragma unroll
            for (int n = 0; n < NBR; ++n) w8[n] *= inv;
        }

        #pragma unroll
        for (int idx = tid; idx < 576; idx += 256) {
            const int t = idx >> 6, c = idx & 63;
            float acc = 0.f;
            #pragma unroll
            for (int n = 0; n < NBR; ++n)
                acc += w8[n] * lw[n * 576 + c * 9 + t];
            wfilt[(((long)(b * 9 + t) * COUT + o) << 6) + c] = f2bf(acc);
        }
        if (tid == 0) {
            float ab = 0.f;
            #pragma unroll
            for (int n = 0; n < NBR; ++n) ab += w8[n] * filt_b[n * COUT + o];
            cbias[b * COUT + o] = ab;
        }
    } else {
        // ---------------- cast branch: build one tile's swizzled bf16 slab ----------------
        const int id = blockIdx.x - NTILES;
        const int tx = id & 3, ty = (id >> 2) & 15, b = id >> 6;
        const int h0 = ty * RT, w0 = tx * WT;
        unsigned short* dst = xt + (long)id * SLABUS;
        const long cs = (long)HH * WW;

        for (int t = tid; t < SLABPIX * 8; t += 256) {      // 2720 16B chunks
            const int pix = t >> 3, q = t & 7;
            const int s = pix / SLABW;
            const int p = pix - s * SLABW;
            const int h = h0 + s - 1, w = w0 + p - 1;
            uint4 v; v.x = v.y = v.z = v.w = 0u;
            if (h >= 0 && h < HH && w >= 0 && w < WW) {
                const float* px = x + (((long)(b * CIN + q * 8)) * HH + h) * WW + w;
                v.x = f2bf_hi(px[0])      | (f2bf_hi(px[cs])     << 16);
                v.y = f2bf_hi(px[2 * cs]) | (f2bf_hi(px[3 * cs]) << 16);
                v.z = f2bf_hi(px[4 * cs]) | (f2bf_hi(px[5 * cs]) << 16);
                v.w = f2bf_hi(px[6 * cs]) | (f2bf_hi(px[7 * cs]) << 16);
            }
            // inverse-swizzled store: chunk slot = q ^ (pix&7) within the 128B pixel
            *(uint4*)&dst[(size_t)(pix * 8 + (q ^ (pix & 7))) * 8] = v;
        }
    }
}

// ---------------- kernel 2: conv — pure global_load_lds staging, swizzled b128 reads ----
__global__ __launch_bounds__(256, 3)
void k_conv(const unsigned short* __restrict__ xt,
            const unsigned short* __restrict__ wfilt,
            const float* __restrict__ cbias,
            float* __restrict__ out) {
    __shared__ uint4 lx4[SLABPIX * 8];                    // 43520 B, linear copy of slab
    unsigned short* lx = (unsigned short*)lx4;

    const int b  = blockIdx.z;
    const int ty = blockIdx.y, tx = blockIdx.x;
    const int h0 = ty * RT;
    const int w0 = tx * WT;
    const int tid = threadIdx.x;
    const int tile = (b * 16 + ty) * 4 + tx;
    const unsigned short* src = xt + (long)tile * SLABUS;

    // ---- stage slab: 2720 chunks, fire-and-forget DMA (10 full rounds + 160 tail) ----
    #pragma unroll
    for (int k = 0; k < 10; ++k) {
        const int t = tid + k * 256;
        gload_lds16(src + (size_t)t * 8, lx + (size_t)t * 8);
    }
    if (tid < SLABPIX * 8 - 2560) {
        const int t = tid + 2560;
        gload_lds16(src + (size_t)t * 8, lx + (size_t)t * 8);
    }

    const int lane = tid & 63;
    const int wave = tid >> 6;
    const int l31  = lane & 31;
    const int lh   = lane >> 5;
    const int r0   = wave * 2;

    const unsigned short* wf = wfilt + (long)b * 9 * COUT * CIN;

    // prefetch tap-0 A fragments (overlaps the LDS DMA)
    short8 A0[4], A1[4];
    #pragma unroll
    for (int cc = 0; cc < 4; ++cc) {
        A0[cc] = gld_frag(wf + l31 * CIN + cc * 16 + lh * 8);
        A1[cc] = gld_frag(wf + (32 + l31) * CIN + cc * 16 + lh * 8);
    }

    // bias-initialized accumulators (C/D row m = (i&3)+8*(i>>2)+4*lh)
    f32x16 acc00, acc01, acc10, acc11;
    #pragma unroll
    for (int i = 0; i < 16; ++i) {
        const int m = (i & 3) + 8 * (i >> 2) + 4 * lh;
        const float b0 = cbias[b * COUT + m];
        const float b1 = cbias[b * COUT + 32 + m];
        acc00[i] = b0; acc01[i] = b0;
        acc10[i] = b1; acc11[i] = b1;
    }

    __syncthreads();   // compiler inserts vmcnt(0) drain of the load_lds queue here

    #pragma unroll
    for (int tap = 0; tap < 9; ++tap) {
        // prefetch next tap's A into fresh registers BEFORE this tap's MFMAs
        short8 nA0[4], nA1[4];
        if (tap < 8) {
            const unsigned short* wn = wf + (long)(tap + 1) * COUT * CIN;
            #pragma unroll
            for (int cc = 0; cc < 4; ++cc) {
                nA0[cc] = gld_frag(wn + l31 * CIN + cc * 16 + lh * 8);
                nA1[cc] = gld_frag(wn + (32 + l31) * CIN + cc * 16 + lh * 8);
            }
        }
        const int kh = tap / 3, kw = tap % 3;
        const int pix0 = (r0 + kh) * SLABW + l31 + kw;
        const int pix1 = pix0 + SLABW;
        #pragma unroll
        for (int cc = 0; cc < 4; ++cc) {
            const int q = cc * 2 + lh;
            short8 b0 = lds_frag128(lx + (size_t)pix0 * 64 + ((q ^ (pix0 & 7)) << 3));
            short8 b1 = lds_frag128(lx + (size_t)pix1 * 64 + ((q ^ (pix1 & 7)) << 3));
            acc00 = __builtin_amdgcn_mfma_f32_32x32x16_bf16(A0[cc], b0, acc00, 0, 0, 0);
            acc01 = __builtin_amdgcn_mfma_f32_32x32x16_bf16(A0[cc], b1, acc01, 0, 0, 0);
            acc10 = __builtin_amdgcn_mfma_f32_32x32x16_bf16(A1[cc], b0, acc10, 0, 0, 0);
            acc11 = __builtin_amdgcn_mfma_f32_32x32x16_bf16(A1[cc], b1, acc11, 0, 0, 0);
        }
        #pragma unroll
        for (int cc = 0; cc < 4; ++cc) { A0[cc] = nA0[cc]; A1[cc] = nA1[cc]; }
    }

    #pragma unroll
    for (int cb = 0; cb < 2; ++cb) {
        #pragma unroll
        for (int pb = 0; pb < 2; ++pb) {
            const f32x16 v = cb == 0 ? (pb == 0 ? acc00 : acc01)
                                     : (pb == 0 ? acc10 : acc11);
            const int hrow = h0 + r0 + pb;
            float* op = out + (((long)(b * COUT + cb * 32) * HH + hrow) * WW + w0 + l31);
            #pragma unroll
            for (int i = 0; i < 16; ++i) {
                const int m = (i & 3) + 8 * (i >> 2) + 4 * lh;
                op[(long)m * HH * WW] = v[i];
            }
        }
    }
}

extern "C" void kernel_launch(void* const* d_in, const int* in_sizes, int n_in,
                              void* d_out, int out_size, void* d_ws, size_t ws_size,
                              hipStream_t stream) {
    const float* x      = (const float*)d_in[0];
    const float* cond   = (const float*)d_in[1];
    const float* filt_w = (const float*)d_in[2];
    const float* filt_b = (const float*)d_in[3];
    const float* sel_w  = (const float*)d_in[4];
    const float* sel_b  = (const float*)d_in[5];
    float* out = (float*)d_out;

    // ws: cbias [16][64] f32 @0; wfilt [16][9][64][64] bf16 @4096;
    //     xt: 1024 tile slabs x 43520 B @1183744  -> total ~45.8 MB
    float*          cbias = (float*)d_ws;
    unsigned short* wfilt = (unsigned short*)((char*)d_ws + 4096);
    unsigned short* xt    = (unsigned short*)((char*)d_ws + 4096 + 1179648);

    k_pc<<<NTILES * 2, 256, 0, stream>>>(cond, sel_w, sel_b, filt_w, filt_b, x,
                                         wfilt, cbias, xt);

    dim3 grid(WW / WT, HH / RT, BATCH);                  // 4 x 16 x 16 = 1024 blocks
    k_conv<<<grid, 256, 0, stream>>>(xt, wfilt, cbias, out);
}

// Round 4
// 193.705 us; speedup vs baseline: 1.0611x; 1.0611x over previous
//
#include <hip/hip_runtime.h>
#include <stdint.h>

#define BATCH 16
#define CIN   64
#define COUT  64
#define NBR   8
#define HH    128
#define WW    128

typedef __attribute__((ext_vector_type(8)))  short short8;
typedef __attribute__((ext_vector_type(16))) float f32x16;

// round-half-up f32->bf16 (inputs are tame normals; 3.4x error headroom measured)
__device__ __forceinline__ unsigned int f2bf_hi(float f) {
    union { float f; uint32_t u; } v; v.f = f;
    return (v.u + 0x8000u) >> 16;
}
// RNE version
__device__ __forceinline__ unsigned short f2bf(float f) {
    union { float f; uint32_t u; } v; v.f = f;
    uint32_t u = v.u;
    return (unsigned short)((u + 0x7FFFu + ((u >> 16) & 1u)) >> 16);
}
__device__ __forceinline__ short8 gld_frag(const unsigned short* p) {
    union { uint4 u; short8 s; } t;
    t.u = *(const uint4*)p;            // 16B aligned
    return t.s;
}
__device__ __forceinline__ short8 lds_frag(const unsigned short* p) {
    union { uint2 u[2]; short8 s; } t;
    t.u[0] = *(const uint2*)p;         // 8B aligned
    t.u[1] = *(const uint2*)(p + 4);
    return t.s;
}

// ---------------- kernel 1: softmax + filter/bias combine (1024 blocks) ----------------
__global__ __launch_bounds__(256)
void k_prep(const float* __restrict__ cond,
            const float* __restrict__ sel_w,
            const float* __restrict__ sel_b,
            const float* __restrict__ filt_w,
            const float* __restrict__ filt_b,
            unsigned short* __restrict__ wfilt,
            float* __restrict__ cbias) {
    __shared__ float4 lw4[NBR * 144];          // 8 x 576 floats = 18432 B
    __shared__ float lg[NBR];
    float* lw = (float*)lw4;

    const int blk = blockIdx.x;                // 1024
    const int b = blk >> 6, o = blk & 63;
    const int tid = threadIdx.x;

    const float4* src4 = (const float4*)filt_w;
    #pragma unroll
    for (int i = tid; i < NBR * 144; i += 256)
        lw4[i] = src4[((i / 144) * COUT + o) * 144 + (i % 144)];

    {
        const int lane = tid & 63, w = tid >> 6;
        const float c0 = cond[b * CIN + lane];
        #pragma unroll
        for (int k = 0; k < 2; ++k) {
            const int n = w + k * 4;
            float p = c0 * sel_w[n * CIN + lane];
            #pragma unroll
            for (int off = 32; off > 0; off >>= 1)
                p += __shfl_down(p, off, 64);
            if (lane == 0) lg[n] = p + sel_b[n];
        }
    }
    __syncthreads();

    float w8[NBR];
    {
        float m = -1e30f;
        #pragma unroll
        for (int n = 0; n < NBR; ++n) m = fmaxf(m, lg[n]);
        float s = 0.f;
        #pragma unroll
        for (int n = 0; n < NBR; ++n) { w8[n] = __expf(lg[n] - m); s += w8[n]; }
        const float inv = 1.f / s;
        #pragma unroll
        for (int n = 0; n < NBR; ++n) w8[n] *= inv;
    }

    #pragma unroll
    for (int idx = tid; idx < 576; idx += 256) {
        const int t = idx >> 6, c = idx & 63;
        float acc = 0.f;
        #pragma unroll
        for (int n = 0; n < NBR; ++n)
            acc += w8[n] * lw[n * 576 + c * 9 + t];
        wfilt[(((long)(b * 9 + t) * COUT + o) << 6) + c] = f2bf(acc);
    }
    if (tid == 0) {
        float ab = 0.f;
        #pragma unroll
        for (int n = 0; n < NBR; ++n) ab += w8[n] * filt_b[n * COUT + o];
        cbias[b * COUT + o] = ab;
    }
}

// ---------------- kernel 2: fused conv, single pass over f32 x ----------------
#define RT 8
#define WT 32
#define SLABW 34          // WT + 2 halo
#define SLABR 10          // RT + 2 halo
#define PSTR  68          // ushorts per pixel (64 ch + 4 pad; b64 reads are 2-way/free)
#define NTASK (SLABR * 32 * 10)   // 3200 staging tasks

__global__ __launch_bounds__(256, 3)
void k_conv(const float* __restrict__ x,
            const unsigned short* __restrict__ wfilt,
            const float* __restrict__ cbias,
            float* __restrict__ out) {
    __shared__ unsigned short lx[SLABR * SLABW * PSTR];   // 46240 B; 3 blocks/CU

    const int b  = blockIdx.z;
    const int h0 = blockIdx.y * RT;
    const int w0 = blockIdx.x * WT;
    const int tid = threadIdx.x;

    // ---- stage x slab, software-pipelined: issue next loads before converting current ----
    // task = (s, channel-pair, j): loads float4 (4 w) from 2 channels, packs bf16x2, stores.
    float4 v0, v1;
    {   // prologue: load task = tid (always < NTASK)
        const int j = tid % 10, r = tid / 10, cp = r & 31, s = r >> 5;
        const int hin = h0 + s - 1, wbase = w0 - 4 + j * 4;
        v0.x = v0.y = v0.z = v0.w = 0.f; v1 = v0;
        if (hin >= 0 && hin < HH && wbase >= 0 && wbase < WW) {
            const float* px = x + (((long)(b * CIN + cp * 2) * HH + hin) * WW + wbase);
            v0 = *(const float4*)px;
            v1 = *(const float4*)(px + (long)HH * WW);
        }
    }
    int curt = tid;
    #pragma unroll
    for (int k = 0; k < 13; ++k) {
        const int nxt = curt + 256;
        float4 n0, n1;
        n0.x = n0.y = n0.z = n0.w = 0.f; n1 = n0;
        if (k < 12 && nxt < NTASK) {               // issue next iteration's loads EARLY
            const int j = nxt % 10, r = nxt / 10, cp = r & 31, s = r >> 5;
            const int hin = h0 + s - 1, wbase = w0 - 4 + j * 4;
            if (hin >= 0 && hin < HH && wbase >= 0 && wbase < WW) {
                const float* px = x + (((long)(b * CIN + cp * 2) * HH + hin) * WW + wbase);
                n0 = *(const float4*)px;
                n1 = *(const float4*)(px + (long)HH * WW);
            }
        }
        if (curt < NTASK) {                        // convert + store current (hides load latency)
            const int j = curt % 10, r = curt / 10, cp = r & 31, s = r >> 5;
            const int c = cp * 2;
            unsigned int d[4];
            d[0] = f2bf_hi(v0.x) | (f2bf_hi(v1.x) << 16);
            d[1] = f2bf_hi(v0.y) | (f2bf_hi(v1.y) << 16);
            d[2] = f2bf_hi(v0.z) | (f2bf_hi(v1.z) << 16);
            d[3] = f2bf_hi(v0.w) | (f2bf_hi(v1.w) << 16);
            #pragma unroll
            for (int i = 0; i < 4; ++i) {
                const int p = j * 4 - 3 + i;
                if (p >= 0 && p < SLABW)
                    *(unsigned int*)&lx[(s * SLABW + p) * PSTR + c] = d[i];
            }
        }
        curt = nxt; v0 = n0; v1 = n1;
    }

    const int lane = tid & 63;
    const int wave = tid >> 6;
    const int l31  = lane & 31;
    const int lh   = lane >> 5;
    const int r0   = wave * 2;

    const unsigned short* wf = wfilt + (long)b * 9 * COUT * CIN;

    // prefetch tap-0 A fragments (independent of LDS staging -> overlaps it)
    short8 A0[4], A1[4];
    #pragma unroll
    for (int cc = 0; cc < 4; ++cc) {
        A0[cc] = gld_frag(wf + l31 * CIN + cc * 16 + lh * 8);
        A1[cc] = gld_frag(wf + (32 + l31) * CIN + cc * 16 + lh * 8);
    }

    // bias-initialized accumulators (C/D row m = (i&3)+8*(i>>2)+4*lh)
    f32x16 acc00, acc01, acc10, acc11;
    #pragma unroll
    for (int i = 0; i < 16; ++i) {
        const int m = (i & 3) + 8 * (i >> 2) + 4 * lh;
        const float b0 = cbias[b * COUT + m];
        const float b1 = cbias[b * COUT + 32 + m];
        acc00[i] = b0; acc01[i] = b0;
        acc10[i] = b1; acc11[i] = b1;
    }

    __syncthreads();

    #pragma unroll
    for (int tap = 0; tap < 9; ++tap) {
        // prefetch next tap's A into fresh registers BEFORE this tap's MFMAs
        short8 nA0[4], nA1[4];
        if (tap < 8) {
            const unsigned short* wn = wf + (long)(tap + 1) * COUT * CIN;
            #pragma unroll
            for (int cc = 0; cc < 4; ++cc) {
                nA0[cc] = gld_frag(wn + l31 * CIN + cc * 16 + lh * 8);
                nA1[cc] = gld_frag(wn + (32 + l31) * CIN + cc * 16 + lh * 8);
            }
        }
        const int kh = tap / 3, kw = tap % 3;
        __builtin_amdgcn_s_setprio(1);
        #pragma unroll
        for (int cc = 0; cc < 4; ++cc) {
            const int kofs = cc * 16 + lh * 8;
            short8 b0 = lds_frag(&lx[((r0     + kh) * SLABW + l31 + kw) * PSTR + kofs]);
            short8 b1 = lds_frag(&lx[((r0 + 1 + kh) * SLABW + l31 + kw) * PSTR + kofs]);
            acc00 = __builtin_amdgcn_mfma_f32_32x32x16_bf16(A0[cc], b0, acc00, 0, 0, 0);
            acc01 = __builtin_amdgcn_mfma_f32_32x32x16_bf16(A0[cc], b1, acc01, 0, 0, 0);
            acc10 = __builtin_amdgcn_mfma_f32_32x32x16_bf16(A1[cc], b0, acc10, 0, 0, 0);
            acc11 = __builtin_amdgcn_mfma_f32_32x32x16_bf16(A1[cc], b1, acc11, 0, 0, 0);
        }
        __builtin_amdgcn_s_setprio(0);
        #pragma unroll
        for (int cc = 0; cc < 4; ++cc) { A0[cc] = nA0[cc]; A1[cc] = nA1[cc]; }
    }

    #pragma unroll
    for (int cb = 0; cb < 2; ++cb) {
        #pragma unroll
        for (int pb = 0; pb < 2; ++pb) {
            const f32x16 v = cb == 0 ? (pb == 0 ? acc00 : acc01)
                                     : (pb == 0 ? acc10 : acc11);
            const int hrow = h0 + r0 + pb;
            float* op = out + (((long)(b * COUT + cb * 32) * HH + hrow) * WW + w0 + l31);
            #pragma unroll
            for (int i = 0; i < 16; ++i) {
                const int m = (i & 3) + 8 * (i >> 2) + 4 * lh;
                op[(long)m * HH * WW] = v[i];
            }
        }
    }
}

extern "C" void kernel_launch(void* const* d_in, const int* in_sizes, int n_in,
                              void* d_out, int out_size, void* d_ws, size_t ws_size,
                              hipStream_t stream) {
    const float* x      = (const float*)d_in[0];
    const float* cond   = (const float*)d_in[1];
    const float* filt_w = (const float*)d_in[2];
    const float* filt_b = (const float*)d_in[3];
    const float* sel_w  = (const float*)d_in[4];
    const float* sel_b  = (const float*)d_in[5];
    float* out = (float*)d_out;

    // ws: cbias [16][64] f32 @0; wfilt [16][9][64][64] bf16 @4096
    float*          cbias = (float*)d_ws;
    unsigned short* wfilt = (unsigned short*)((char*)d_ws + 4096);

    k_prep<<<BATCH * COUT, 256, 0, stream>>>(cond, sel_w, sel_b, filt_w, filt_b, wfilt, cbias);

    dim3 grid(WW / WT, HH / RT, BATCH);                  // 4 x 16 x 16 = 1024 blocks
    k_conv<<<grid, 256, 0, stream>>>(x, wfilt, cbias, out);
}

// Round 5
// 181.163 us; speedup vs baseline: 1.1346x; 1.0692x over previous
//
#include <hip/hip_runtime.h>
#include <stdint.h>

#define BATCH 16
#define CIN   64
#define COUT  64
#define NBR   8
#define HH    128
#define WW    128
#define XBH   130              // padded height
#define XBW   130              // padded width
#define PSTR  68               // ushorts per pixel in xb AND in LDS (64 ch + 4 pad)
#define NTILES 1024

typedef __attribute__((ext_vector_type(8)))  short short8;
typedef __attribute__((ext_vector_type(16))) float f32x16;

// round-half-up f32->bf16 (inputs are tame normals; 3.4x error headroom measured)
__device__ __forceinline__ unsigned int f2bf_hi(float f) {
    union { float f; uint32_t u; } v; v.f = f;
    return (v.u + 0x8000u) >> 16;
}
// RNE version
__device__ __forceinline__ unsigned short f2bf(float f) {
    union { float f; uint32_t u; } v; v.f = f;
    uint32_t u = v.u;
    return (unsigned short)((u + 0x7FFFu + ((u >> 16) & 1u)) >> 16);
}
__device__ __forceinline__ short8 gld_frag(const unsigned short* p) {
    union { uint4 u; short8 s; } t;
    t.u = *(const uint4*)p;            // 16B aligned
    return t.s;
}
__device__ __forceinline__ short8 lds_frag(const unsigned short* p) {
    union { uint2 u[2]; short8 s; } t;
    t.u[0] = *(const uint2*)p;         // 8B aligned
    t.u[1] = *(const uint2*)(p + 4);
    return t.s;
}
// async global->LDS, 16B per lane; LDS dest is wave-uniform base + lane*16
__device__ __forceinline__ void gload_lds16(const unsigned short* g, unsigned short* l) {
    __builtin_amdgcn_global_load_lds(
        (const __attribute__((address_space(1))) unsigned int*)g,
        (__attribute__((address_space(3))) unsigned int*)l, 16, 0, 0);
}

// -------- kernel 1: fused {softmax+filter combine (blocks<1024)} | {x->xb cast} --------
// xb[b][h'][w'][68] bf16, 136 B/pixel; rows 0/129 and cols 0/129 are zero halo.
__global__ __launch_bounds__(256)
void k_pc(const float* __restrict__ cond,
          const float* __restrict__ sel_w,
          const float* __restrict__ sel_b,
          const float* __restrict__ filt_w,
          const float* __restrict__ filt_b,
          const float* __restrict__ x,
          unsigned short* __restrict__ wfilt,
          float* __restrict__ cbias,
          unsigned short* __restrict__ xb) {
    __shared__ float4 lw4[NBR * 144];          // 18432 B (prep branch only)
    __shared__ float lg[NBR];
    const int tid = threadIdx.x;

    if (blockIdx.x < NTILES) {
        // ---------------- prep branch (unchanged, verified) ----------------
        float* lw = (float*)lw4;
        const int blk = blockIdx.x;
        const int b = blk >> 6, o = blk & 63;

        const float4* src4 = (const float4*)filt_w;
        #pragma unroll
        for (int i = tid; i < NBR * 144; i += 256)
            lw4[i] = src4[((i / 144) * COUT + o) * 144 + (i % 144)];

        {
            const int lane = tid & 63, w = tid >> 6;
            const float c0 = cond[b * CIN + lane];
            #pragma unroll
            for (int k = 0; k < 2; ++k) {
                const int n = w + k * 4;
                float p = c0 * sel_w[n * CIN + lane];
                #pragma unroll
                for (int off = 32; off > 0; off >>= 1)
                    p += __shfl_down(p, off, 64);
                if (lane == 0) lg[n] = p + sel_b[n];
            }
        }
        __syncthreads();

        float w8[NBR];
        {
            float m = -1e30f;
            #pragma unroll
            for (int n = 0; n < NBR; ++n) m = fmaxf(m, lg[n]);
            float s = 0.f;
            #pragma unroll
            for (int n = 0; n < NBR; ++n) { w8[n] = __expf(lg[n] - m); s += w8[n]; }
            const float inv = 1.f / s;
            #pragma unroll
            for (int n = 0; n < NBR; ++n) w8[n] *= inv;
        }

        #pragma unroll
        for (int idx = tid; idx < 576; idx += 256) {
            const int t = idx >> 6, c = idx & 63;
            float acc = 0.f;
            #pragma unroll
            for (int n = 0; n < NBR; ++n)
                acc += w8[n] * lw[n * 576 + c * 9 + t];
            wfilt[(((long)(b * 9 + t) * COUT + o) << 6) + c] = f2bf(acc);
        }
        if (tid == 0) {
            float ab = 0.f;
            #pragma unroll
            for (int n = 0; n < NBR; ++n) ab += w8[n] * filt_b[n * COUT + o];
            cbias[b * COUT + o] = ab;
        }
    } else {
        // ---------------- cast branch: one padded row of xb ----------------
        const int id = blockIdx.x - NTILES;        // 0 .. 16*130-1
        const int hp = id % XBH;
        const int b  = id / XBH;
        unsigned short* dst = xb + (long)(b * XBH + hp) * XBW * PSTR;
        const bool zrow = (hp == 0) || (hp == XBH - 1);
        const int h = hp - 1;
        const long cs = (long)HH * WW;

        for (int t = tid; t < XBW * 8; t += 256) {     // 130 pixels x 8 chunks of 8ch
            const int wp = t >> 3, q = t & 7;
            uint4 v; v.x = v.y = v.z = v.w = 0u;
            if (!zrow && wp != 0 && wp != XBW - 1) {
                const float* px = x + (((long)(b * CIN + q * 8)) * HH + h) * WW + (wp - 1);
                v.x = f2bf_hi(px[0])      | (f2bf_hi(px[cs])     << 16);
                v.y = f2bf_hi(px[2 * cs]) | (f2bf_hi(px[3 * cs]) << 16);
                v.z = f2bf_hi(px[4 * cs]) | (f2bf_hi(px[5 * cs]) << 16);
                v.w = f2bf_hi(px[6 * cs]) | (f2bf_hi(px[7 * cs]) << 16);
            }
            unsigned short* dp = dst + wp * PSTR + q * 8;    // 8B aligned (PSTR*2=136)
            uint2 u0, u1;
            u0.x = v.x; u0.y = v.y; u1.x = v.z; u1.y = v.w;
            *(uint2*)dp       = u0;
            *(uint2*)(dp + 4) = u1;
            if (q == 7) {                                    // zero the 8B pad
                uint2 z; z.x = z.y = 0u;
                *(uint2*)(dst + wp * PSTR + 64) = z;
            }
        }
    }
}

// -------- kernel 2: conv — pure global_load_lds staging of contiguous padded rows --------
#define RT 8
#define WT 32
#define SLABW 34          // WT + 2 halo
#define SLABR 10          // RT + 2 halo
#define ROWUS (SLABW * PSTR)          // 2312 ushorts = 4624 B per slab row (16B multiple)
#define NCHUNK (SLABR * ROWUS / 8)    // 2890 16B chunks per slab

__global__ __launch_bounds__(256, 3)
void k_conv(const unsigned short* __restrict__ xb,
            const unsigned short* __restrict__ wfilt,
            const float* __restrict__ cbias,
            float* __restrict__ out) {
    __shared__ unsigned short lx[SLABR * ROWUS];          // 46240 B; 3 blocks/CU

    const int b  = blockIdx.z;
    const int h0 = blockIdx.y * RT;
    const int w0 = blockIdx.x * WT;
    const int tid = threadIdx.x;

    // ---- stage slab: 10 contiguous 4624B row segments, fire-and-forget DMA ----
    // global row segment start = ((b*130 + h0+row)*130 + w0)*136 B  -> 16B aligned
    const unsigned short* srcb = xb + ((long)(b * XBH + h0) * XBW + w0) * PSTR;
    #pragma unroll
    for (int k = 0; k < 12; ++k) {
        const int t = tid + k * 256;
        if (t < NCHUNK) {
            const int row = t / 289;              // 289 chunks per row (4624/16)
            const int rc  = t - row * 289;
            gload_lds16(srcb + (long)row * (XBW * PSTR) + rc * 8, lx + t * 8);
        }
    }

    const int lane = tid & 63;
    const int wave = tid >> 6;
    const int l31  = lane & 31;
    const int lh   = lane >> 5;
    const int r0   = wave * 2;

    const unsigned short* wf = wfilt + (long)b * 9 * COUT * CIN;

    // prefetch tap-0 A fragments (overlaps the LDS DMA)
    short8 A0[4], A1[4];
    #pragma unroll
    for (int cc = 0; cc < 4; ++cc) {
        A0[cc] = gld_frag(wf + l31 * CIN + cc * 16 + lh * 8);
        A1[cc] = gld_frag(wf + (32 + l31) * CIN + cc * 16 + lh * 8);
    }

    // bias-initialized accumulators (C/D row m = (i&3)+8*(i>>2)+4*lh)
    f32x16 acc00, acc01, acc10, acc11;
    #pragma unroll
    for (int i = 0; i < 16; ++i) {
        const int m = (i & 3) + 8 * (i >> 2) + 4 * lh;
        const float b0 = cbias[b * COUT + m];
        const float b1 = cbias[b * COUT + 32 + m];
        acc00[i] = b0; acc01[i] = b0;
        acc10[i] = b1; acc11[i] = b1;
    }

    __syncthreads();   // compiler drains vmcnt(0) here -> slab + A frags ready

    #pragma unroll
    for (int tap = 0; tap < 9; ++tap) {
        // prefetch next tap's A into fresh registers BEFORE this tap's MFMAs
        short8 nA0[4], nA1[4];
        if (tap < 8) {
            const unsigned short* wn = wf + (long)(tap + 1) * COUT * CIN;
            #pragma unroll
            for (int cc = 0; cc < 4; ++cc) {
                nA0[cc] = gld_frag(wn + l31 * CIN + cc * 16 + lh * 8);
                nA1[cc] = gld_frag(wn + (32 + l31) * CIN + cc * 16 + lh * 8);
            }
        }
        const int kh = tap / 3, kw = tap % 3;
        #pragma unroll
        for (int cc = 0; cc < 4; ++cc) {
            const int kofs = cc * 16 + lh * 8;
            short8 b0 = lds_frag(&lx[((r0     + kh) * SLABW + l31 + kw) * PSTR + kofs]);
            short8 b1 = lds_frag(&lx[((r0 + 1 + kh) * SLABW + l31 + kw) * PSTR + kofs]);
            acc00 = __builtin_amdgcn_mfma_f32_32x32x16_bf16(A0[cc], b0, acc00, 0, 0, 0);
            acc01 = __builtin_amdgcn_mfma_f32_32x32x16_bf16(A0[cc], b1, acc01, 0, 0, 0);
            acc10 = __builtin_amdgcn_mfma_f32_32x32x16_bf16(A1[cc], b0, acc10, 0, 0, 0);
            acc11 = __builtin_amdgcn_mfma_f32_32x32x16_bf16(A1[cc], b1, acc11, 0, 0, 0);
        }
        #pragma unroll
        for (int cc = 0; cc < 4; ++cc) { A0[cc] = nA0[cc]; A1[cc] = nA1[cc]; }
    }

    #pragma unroll
    for (int cb = 0; cb < 2; ++cb) {
        #pragma unroll
        for (int pb = 0; pb < 2; ++pb) {
            const f32x16 v = cb == 0 ? (pb == 0 ? acc00 : acc01)
                                     : (pb == 0 ? acc10 : acc11);
            const int hrow = h0 + r0 + pb;
            float* op = out + (((long)(b * COUT + cb * 32) * HH + hrow) * WW + w0 + l31);
            #pragma unroll
            for (int i = 0; i < 16; ++i) {
                const int m = (i & 3) + 8 * (i >> 2) + 4 * lh;
                op[(long)m * HH * WW] = v[i];
            }
        }
    }
}

extern "C" void kernel_launch(void* const* d_in, const int* in_sizes, int n_in,
                              void* d_out, int out_size, void* d_ws, size_t ws_size,
                              hipStream_t stream) {
    const float* x      = (const float*)d_in[0];
    const float* cond   = (const float*)d_in[1];
    const float* filt_w = (const float*)d_in[2];
    const float* filt_b = (const float*)d_in[3];
    const float* sel_w  = (const float*)d_in[4];
    const float* sel_b  = (const float*)d_in[5];
    float* out = (float*)d_out;

    // ws: cbias [16][64] f32 @0; wfilt [16][9][64][64] bf16 @4096;
    //     xb [16][130][130][68] bf16 @1183744 (36.8 MB) -> total ~38 MB
    float*          cbias = (float*)d_ws;
    unsigned short* wfilt = (unsigned short*)((char*)d_ws + 4096);
    unsigned short* xb    = (unsigned short*)((char*)d_ws + 4096 + 1179648);

    k_pc<<<NTILES + BATCH * XBH, 256, 0, stream>>>(cond, sel_w, sel_b, filt_w, filt_b, x,
                                                   wfilt, cbias, xb);

    dim3 grid(WW / WT, HH / RT, BATCH);                  // 4 x 16 x 16 = 1024 blocks
    k_conv<<<grid, 256, 0, stream>>>(xb, wfilt, cbias, out);
}